// Round 1
// baseline (622.939 us; speedup 1.0000x reference)
//
#include <hip/hip_runtime.h>

#define N_NODES 50000
#define N_EDGES 800000
#define IN_C 256
#define HID_C 512
#define OUT_C 256
#define M_PAD 50048   // 391 * 128, covers 50000 with one padded tile

typedef unsigned short u16;
typedef unsigned int   u32;
typedef u16  u16x4 __attribute__((ext_vector_type(4)));
typedef u16  u16x8 __attribute__((ext_vector_type(8)));
typedef short s16x8 __attribute__((ext_vector_type(8)));   // bf16 MFMA frag (guide §3)
typedef float f32x4 __attribute__((ext_vector_type(4)));

__device__ __forceinline__ float bf2f(u16 h) {
    u32 u = ((u32)h) << 16;
    return __builtin_bit_cast(float, u);
}
__device__ __forceinline__ u16 f2bf(float f) {   // round-to-nearest-even
    u32 u = __builtin_bit_cast(u32, f);
    u32 r = u + 0x7fffu + ((u >> 16) & 1u);
    return (u16)(r >> 16);
}
__device__ __forceinline__ void gload16(const void* g, void* l) {
    __builtin_amdgcn_global_load_lds(
        (const __attribute__((address_space(1))) u32*)g,
        (__attribute__((address_space(3))) u32*)l, 16, 0, 0);
}
__device__ __forceinline__ int swz4(int r) { return (r ^ (r >> 2)) & 3; }

// ---------------- CSR build ----------------
__global__ void k_hist(const int* __restrict__ dst, int* __restrict__ cnt) {
    int e = blockIdx.x * 256 + threadIdx.x;
    if (e < N_EDGES) atomicAdd(&cnt[dst[e]], 1);
}

__global__ void k_partial(const int* __restrict__ cnt, int* __restrict__ bsum) {
    __shared__ int s[256];
    int i = blockIdx.x * 256 + threadIdx.x;
    int v = (i < N_NODES) ? cnt[i] : 0;
    s[threadIdx.x] = v; __syncthreads();
    for (int o = 128; o > 0; o >>= 1) {
        if (threadIdx.x < o) s[threadIdx.x] += s[threadIdx.x + o];
        __syncthreads();
    }
    if (threadIdx.x == 0) bsum[blockIdx.x] = s[0];
}

__global__ void k_scanb(int* __restrict__ bsum, int nb) {
    if (threadIdx.x == 0 && blockIdx.x == 0) {
        int run = 0;
        for (int i = 0; i < nb; i++) { int v = bsum[i]; bsum[i] = run; run += v; }
    }
}

__global__ void k_rowptr(const int* __restrict__ cnt, const int* __restrict__ bsum,
                         int* __restrict__ rp, int* __restrict__ cur) {
    __shared__ int s[256];
    int i = blockIdx.x * 256 + threadIdx.x;
    int v = (i < N_NODES) ? cnt[i] : 0;
    s[threadIdx.x] = v; __syncthreads();
    for (int o = 1; o < 256; o <<= 1) {                     // Hillis-Steele inclusive
        int t = (threadIdx.x >= o) ? s[threadIdx.x - o] : 0;
        __syncthreads();
        s[threadIdx.x] += t;
        __syncthreads();
    }
    int excl = s[threadIdx.x] - v + bsum[blockIdx.x];
    if (i < N_NODES) { rp[i] = excl; cur[i] = excl; }
    if (i == N_NODES - 1) rp[N_NODES] = excl + v;
}

__global__ void k_scatter(const int* __restrict__ src, const int* __restrict__ dst,
                          int* __restrict__ cur, int* __restrict__ col) {
    int e = blockIdx.x * 256 + threadIdx.x;
    if (e < N_EDGES) {
        int d = dst[e];
        int p = atomicAdd(&cur[d], 1);
        col[p] = src[e];
    }
}

// -------------- weight prep: W[K][N] fp32 -> Wt[N][K] bf16 --------------
__global__ void k_wt(const float* __restrict__ w, u16* __restrict__ wt, int K, int N) {
    int idx = blockIdx.x * 256 + threadIdx.x;
    if (idx >= K * N) return;
    int n = idx / K, k = idx - n * K;
    wt[idx] = f2bf(w[(size_t)k * N + n]);
}

// -------------- aggregation kernels (wave per node, CSR gather) --------------
// L1: A0 = bf16((1+eps1)*x + sum_{src in N(n)} x[src]),  256 fp32 channels
__global__ __launch_bounds__(256) void k_agg_l1(
    const float* __restrict__ x, const int* __restrict__ rp,
    const int* __restrict__ col, const float* __restrict__ eps,
    u16* __restrict__ A0) {
    int wave = threadIdx.x >> 6, lane = threadIdx.x & 63;
    int n = blockIdx.x * 4 + wave;
    if (n >= N_NODES) return;
    int rs = rp[n], re = rp[n + 1];
    int c0 = lane * 4;
    float4 acc = make_float4(0.f, 0.f, 0.f, 0.f);
    for (int e = rs; e < re; e++) {
        int s = col[e];
        float4 v = *(const float4*)(x + (size_t)s * IN_C + c0);
        acc.x += v.x; acc.y += v.y; acc.z += v.z; acc.w += v.w;
    }
    float ep = 1.f + eps[0];
    float4 xv = *(const float4*)(x + (size_t)n * IN_C + c0);
    u16x4 o;
    o[0] = f2bf(fmaf(ep, xv.x, acc.x));
    o[1] = f2bf(fmaf(ep, xv.y, acc.y));
    o[2] = f2bf(fmaf(ep, xv.z, acc.z));
    o[3] = f2bf(fmaf(ep, xv.w, acc.w));
    *(u16x4*)(A0 + (size_t)n * IN_C + c0) = o;
}

// L2: A1 = bf16((1+eps2)*h1 + sum h1[src]),  512 bf16 channels, fp32 accumulate
__global__ __launch_bounds__(256) void k_agg_l2(
    const u16* __restrict__ h, const int* __restrict__ rp,
    const int* __restrict__ col, const float* __restrict__ eps,
    u16* __restrict__ A1) {
    int wave = threadIdx.x >> 6, lane = threadIdx.x & 63;
    int n = blockIdx.x * 4 + wave;
    if (n >= N_NODES) return;
    int rs = rp[n], re = rp[n + 1];
    int c0 = lane * 8;
    float acc[8] = {0.f, 0.f, 0.f, 0.f, 0.f, 0.f, 0.f, 0.f};
    for (int e = rs; e < re; e++) {
        int s = col[e];
        u16x8 v = *(const u16x8*)(h + (size_t)s * HID_C + c0);
#pragma unroll
        for (int j = 0; j < 8; j++) acc[j] += bf2f(v[j]);
    }
    float ep = 1.f + eps[0];
    u16x8 hv = *(const u16x8*)(h + (size_t)n * HID_C + c0);
    u16x8 o;
#pragma unroll
    for (int j = 0; j < 8; j++) o[j] = f2bf(fmaf(ep, bf2f(hv[j]), acc[j]));
    *(u16x8*)(A1 + (size_t)n * HID_C + c0) = o;
}

// L3 (post-GEMM): out = (1+eps3)*g3 + sum g3[src] + b3,  256 fp32 channels
__global__ __launch_bounds__(256) void k_agg_l3(
    const float* __restrict__ g, const int* __restrict__ rp,
    const int* __restrict__ col, const float* __restrict__ eps,
    const float* __restrict__ b, float* __restrict__ out) {
    int wave = threadIdx.x >> 6, lane = threadIdx.x & 63;
    int n = blockIdx.x * 4 + wave;
    if (n >= N_NODES) return;
    int rs = rp[n], re = rp[n + 1];
    int c0 = lane * 4;
    float4 acc = make_float4(0.f, 0.f, 0.f, 0.f);
    for (int e = rs; e < re; e++) {
        int s = col[e];
        float4 v = *(const float4*)(g + (size_t)s * OUT_C + c0);
        acc.x += v.x; acc.y += v.y; acc.z += v.z; acc.w += v.w;
    }
    float ep = 1.f + eps[0];
    float4 gv = *(const float4*)(g + (size_t)n * OUT_C + c0);
    float4 bv = *(const float4*)(b + c0);
    float4 o;
    o.x = fmaf(ep, gv.x, acc.x) + bv.x;
    o.y = fmaf(ep, gv.y, acc.y) + bv.y;
    o.z = fmaf(ep, gv.z, acc.z) + bv.z;
    o.w = fmaf(ep, gv.w, acc.w) + bv.w;
    *(float4*)(out + (size_t)n * OUT_C + c0) = o;
}

// -------------- bf16 MFMA GEMM: C[M][N] = A[M][K] @ Wt[N][K]^T --------------
// 128x128 tile, BK=32, 4 waves (2x2), global_load_lds staging with both-sides
// XOR chunk swizzle (rule 21): LDS tile [128 rows][32 bf16], row=64B=4 chunks,
// chunk c' = c ^ swz4(row) gives 2-way (free) bank access on ds_read_b128.
// EPI=0: out bf16 = relu(acc + bias).  EPI=1: out fp32 = acc (no bias/relu).
template <int K, int EPI>
__global__ __launch_bounds__(256, 2) void gemm_k(
    const u16* __restrict__ A, const u16* __restrict__ Wt,
    const float* __restrict__ bias, void* __restrict__ out,
    int N, int grid_n) {
    __shared__ u16 Als[128 * 32];
    __shared__ u16 Bls[128 * 32];
    const int tid  = threadIdx.x;
    const int wave = tid >> 6, lane = tid & 63;
    const int wm = wave >> 1, wn = wave & 1;
    const int bm = blockIdx.x / grid_n, bn = blockIdx.x % grid_n;
    const int m0 = bm * 128, n0 = bn * 128;
    const int sr = lane >> 2, sc = lane & 3;       // staging: 16 rows x 4 chunks
    const int fr = lane & 15, kg = lane >> 4;      // fragment coords

    f32x4 acc[4][4];
#pragma unroll
    for (int i = 0; i < 4; i++)
#pragma unroll
        for (int j = 0; j < 4; j++) acc[i][j] = (f32x4){0.f, 0.f, 0.f, 0.f};

    for (int kk = 0; kk < K; kk += 32) {
#pragma unroll
        for (int i = 0; i < 2; i++) {
            int rl = wave * 32 + i * 16 + sr;
            int c  = sc ^ swz4(rl);                 // pre-swizzled global source
            gload16(A  + (size_t)(m0 + rl) * K + kk + c * 8,
                    &Als[(wave * 32 + i * 16) * 32]);
            gload16(Wt + (size_t)(n0 + rl) * K + kk + c * 8,
                    &Bls[(wave * 32 + i * 16) * 32]);
        }
        asm volatile("s_waitcnt vmcnt(0)" ::: "memory");
        __syncthreads();

        s16x8 af[4], bfr[4];
#pragma unroll
        for (int mi = 0; mi < 4; mi++) {
            int r = wm * 64 + mi * 16 + fr;
            int c = kg ^ swz4(r);                   // swizzled read
            af[mi] = *(const s16x8*)&Als[r * 32 + c * 8];
        }
#pragma unroll
        for (int ni = 0; ni < 4; ni++) {
            int r = wn * 64 + ni * 16 + fr;
            int c = kg ^ swz4(r);
            bfr[ni] = *(const s16x8*)&Bls[r * 32 + c * 8];
        }
#pragma unroll
        for (int mi = 0; mi < 4; mi++)
#pragma unroll
            for (int ni = 0; ni < 4; ni++)
                acc[mi][ni] = __builtin_amdgcn_mfma_f32_16x16x32_bf16(
                    af[mi], bfr[ni], acc[mi][ni], 0, 0, 0);
        __syncthreads();
    }

    // epilogue: C row = kg*4 + j, col = fr (m89/m91-verified C/D layout)
#pragma unroll
    for (int ni = 0; ni < 4; ni++) {
        int cn = n0 + wn * 64 + ni * 16 + fr;
        float bv = 0.f;
        if constexpr (EPI == 0) bv = bias[cn];
#pragma unroll
        for (int mi = 0; mi < 4; mi++) {
            int rb = m0 + wm * 64 + mi * 16 + kg * 4;
#pragma unroll
            for (int j = 0; j < 4; j++) {
                int r = rb + j;
                if (r < N_NODES) {
                    float v = acc[mi][ni][j];
                    if constexpr (EPI == 0) {
                        v += bv;
                        v = v > 0.f ? v : 0.f;
                        ((u16*)out)[(size_t)r * N + cn] = f2bf(v);
                    } else {
                        ((float*)out)[(size_t)r * N + cn] = v;
                    }
                }
            }
        }
    }
}

// ---------------- launch ----------------
extern "C" void kernel_launch(void* const* d_in, const int* in_sizes, int n_in,
                              void* d_out, int out_size, void* d_ws, size_t ws_size,
                              hipStream_t stream) {
    const float* x    = (const float*)d_in[0];
    const int*   src  = (const int*)d_in[1];
    const int*   dst  = (const int*)d_in[2];
    const float* w1   = (const float*)d_in[3];
    const float* b1   = (const float*)d_in[4];
    const float* eps1 = (const float*)d_in[5];
    const float* w2   = (const float*)d_in[6];
    const float* b2   = (const float*)d_in[7];
    const float* eps2 = (const float*)d_in[8];
    const float* w3   = (const float*)d_in[9];
    const float* b3   = (const float*)d_in[10];
    const float* eps3 = (const float*)d_in[11];

    char* ws = (char*)d_ws;
    size_t off = 0;
    auto take = [&](size_t bytes) {
        char* p = ws + off;
        off += (bytes + 255) & ~(size_t)255;
        return p;
    };
    int* cnt  = (int*)take((size_t)N_NODES * 4);
    int* rp   = (int*)take((size_t)(N_NODES + 1) * 4);
    int* cur  = (int*)take((size_t)N_NODES * 4);
    int* bsum = (int*)take(256 * 4);
    int* col  = (int*)take((size_t)N_EDGES * 4);
    u16* w1t  = (u16*)take((size_t)IN_C * HID_C * 2);
    u16* w2t  = (u16*)take((size_t)HID_C * HID_C * 2);
    u16* w3t  = (u16*)take((size_t)HID_C * OUT_C * 2);
    u16* A0   = (u16*)take((size_t)M_PAD * IN_C * 2);
    u16* h1   = (u16*)take((size_t)M_PAD * HID_C * 2);
    u16* A1   = (u16*)take((size_t)M_PAD * HID_C * 2);
    u16*   h2 = h1;          // GEMM2 reads only A1 -> safe alias
    float* g3 = (float*)A1;  // GEMM3 reads only h2 -> safe alias (same byte size)

    const int NB = 196;  // ceil(50000/256)

    hipMemsetAsync(cnt, 0, (size_t)N_NODES * 4, stream);
    k_hist   <<<(N_EDGES + 255) / 256, 256, 0, stream>>>(dst, cnt);
    k_partial<<<NB, 256, 0, stream>>>(cnt, bsum);
    k_scanb  <<<1, 64, 0, stream>>>(bsum, NB);
    k_rowptr <<<NB, 256, 0, stream>>>(cnt, bsum, rp, cur);
    k_scatter<<<(N_EDGES + 255) / 256, 256, 0, stream>>>(src, dst, cur, col);

    k_wt<<<(IN_C * HID_C + 255) / 256, 256, 0, stream>>>(w1, w1t, IN_C, HID_C);
    k_wt<<<(HID_C * HID_C + 255) / 256, 256, 0, stream>>>(w2, w2t, HID_C, HID_C);
    k_wt<<<(HID_C * OUT_C + 255) / 256, 256, 0, stream>>>(w3, w3t, HID_C, OUT_C);

    // layer 1: aggregate (256ch) then GEMM -> h1 = relu(A0 @ W1 + b1)
    k_agg_l1<<<12500, 256, 0, stream>>>(x, rp, col, eps1, A0);
    gemm_k<IN_C, 0><<<391 * (HID_C / 128), 256, 0, stream>>>(
        A0, w1t, b1, h1, HID_C, HID_C / 128);

    // layer 2: aggregate (512ch) then GEMM -> h2 = relu(A1 @ W2 + b2)
    k_agg_l2<<<12500, 256, 0, stream>>>(h1, rp, col, eps2, A1);
    gemm_k<HID_C, 0><<<391 * (HID_C / 128), 256, 0, stream>>>(
        A1, w2t, b2, h2, HID_C, HID_C / 128);

    // layer 3: GEMM first (g3 = h2 @ W3, no bias), then aggregate (256ch) + bias
    gemm_k<HID_C, 1><<<391 * (OUT_C / 128), 256, 0, stream>>>(
        h2, w3t, nullptr, g3, OUT_C, OUT_C / 128);
    k_agg_l3<<<12500, 256, 0, stream>>>(g3, rp, col, eps3, b3, (float*)d_out);
}

// Round 2
// 556.718 us; speedup vs baseline: 1.1189x; 1.1189x over previous
//
#include <hip/hip_runtime.h>

#define N_NODES 50000
#define N_EDGES 800000
#define IN_C 256
#define HID_C 512
#define OUT_C 256
#define M_PAD 50048   // 391 * 128, covers 50000 with one padded tile

typedef unsigned short u16;
typedef unsigned int   u32;
typedef u16  u16x4 __attribute__((ext_vector_type(4)));
typedef u16  u16x8 __attribute__((ext_vector_type(8)));
typedef short s16x8 __attribute__((ext_vector_type(8)));   // bf16 MFMA frag (guide §3)
typedef float f32x4 __attribute__((ext_vector_type(4)));

__device__ __forceinline__ float bf2f(u16 h) {
    u32 u = ((u32)h) << 16;
    return __builtin_bit_cast(float, u);
}
__device__ __forceinline__ u16 f2bf(float f) {   // round-to-nearest-even
    u32 u = __builtin_bit_cast(u32, f);
    u32 r = u + 0x7fffu + ((u >> 16) & 1u);
    return (u16)(r >> 16);
}
__device__ __forceinline__ void gload16(const void* g, void* l) {
    __builtin_amdgcn_global_load_lds(
        (const __attribute__((address_space(1))) u32*)g,
        (__attribute__((address_space(3))) u32*)l, 16, 0, 0);
}
__device__ __forceinline__ int swz4(int r) { return (r ^ (r >> 2)) & 3; }

// ---------------- CSR build ----------------
__global__ void k_hist(const int* __restrict__ dst, int* __restrict__ cnt) {
    int e = blockIdx.x * 256 + threadIdx.x;
    if (e < N_EDGES) atomicAdd(&cnt[dst[e]], 1);
}

__global__ void k_partial(const int* __restrict__ cnt, int* __restrict__ bsum) {
    __shared__ int s[256];
    int i = blockIdx.x * 256 + threadIdx.x;
    int v = (i < N_NODES) ? cnt[i] : 0;
    s[threadIdx.x] = v; __syncthreads();
    for (int o = 128; o > 0; o >>= 1) {
        if (threadIdx.x < o) s[threadIdx.x] += s[threadIdx.x + o];
        __syncthreads();
    }
    if (threadIdx.x == 0) bsum[blockIdx.x] = s[0];
}

// parallel exclusive scan of nb (<=256) block sums, single block of 256
__global__ void k_scanb(int* __restrict__ bsum, int nb) {
    __shared__ int s[256];
    int i = threadIdx.x;
    int v = (i < nb) ? bsum[i] : 0;
    s[i] = v; __syncthreads();
    for (int o = 1; o < 256; o <<= 1) {
        int t = (i >= o) ? s[i - o] : 0;
        __syncthreads();
        s[i] += t;
        __syncthreads();
    }
    if (i < nb) bsum[i] = s[i] - v;   // exclusive
}

__global__ void k_rowptr(const int* __restrict__ cnt, const int* __restrict__ bsum,
                         int* __restrict__ rp, int* __restrict__ cur) {
    __shared__ int s[256];
    int i = blockIdx.x * 256 + threadIdx.x;
    int v = (i < N_NODES) ? cnt[i] : 0;
    s[threadIdx.x] = v; __syncthreads();
    for (int o = 1; o < 256; o <<= 1) {                     // Hillis-Steele inclusive
        int t = (threadIdx.x >= o) ? s[threadIdx.x - o] : 0;
        __syncthreads();
        s[threadIdx.x] += t;
        __syncthreads();
    }
    int excl = s[threadIdx.x] - v + bsum[blockIdx.x];
    if (i < N_NODES) { rp[i] = excl; cur[i] = excl; }
    if (i == N_NODES - 1) rp[N_NODES] = excl + v;
}

__global__ void k_scatter(const int* __restrict__ src, const int* __restrict__ dst,
                          int* __restrict__ cur, int* __restrict__ col) {
    int e = blockIdx.x * 256 + threadIdx.x;
    if (e < N_EDGES) {
        int d = dst[e];
        int p = atomicAdd(&cur[d], 1);
        col[p] = src[e];
    }
}

// -------------- weight prep: W[K][N] fp32 -> Wt[N][K] bf16 --------------
__global__ void k_wt(const float* __restrict__ w, u16* __restrict__ wt, int K, int N) {
    int idx = blockIdx.x * 256 + threadIdx.x;
    if (idx >= K * N) return;
    int n = idx / K, k = idx - n * K;
    wt[idx] = f2bf(w[(size_t)k * N + n]);
}

// -------------- x fp32 -> bf16 (halves gather bytes in agg_l1) --------------
__global__ void k_x2bf(const float* __restrict__ x, u16* __restrict__ xb) {
    int i = blockIdx.x * 256 + threadIdx.x;
    if (i < N_NODES * IN_C / 4) {
        float4 v = ((const float4*)x)[i];
        u16x4 o;
        o[0] = f2bf(v.x); o[1] = f2bf(v.y); o[2] = f2bf(v.z); o[3] = f2bf(v.w);
        ((u16x4*)xb)[i] = o;
    }
}

// -------------- aggregation kernels (wave per node, CSR gather) --------------
// L1: A0 = bf16((1+eps1)*xb + sum_{src in N(n)} xb[src]),  256 bf16 channels
__global__ __launch_bounds__(256) void k_agg_l1(
    const u16* __restrict__ xb, const int* __restrict__ rp,
    const int* __restrict__ col, const float* __restrict__ eps,
    u16* __restrict__ A0) {
    int wave = threadIdx.x >> 6, lane = threadIdx.x & 63;
    int n = blockIdx.x * 4 + wave;
    if (n >= N_NODES) return;
    int rs = rp[n], re = rp[n + 1];
    int c0 = lane * 4;
    float acc[4] = {0.f, 0.f, 0.f, 0.f};
    for (int e = rs; e < re; e++) {
        int s = col[e];
        u16x4 v = *(const u16x4*)(xb + (size_t)s * IN_C + c0);
#pragma unroll
        for (int j = 0; j < 4; j++) acc[j] += bf2f(v[j]);
    }
    float ep = 1.f + eps[0];
    u16x4 xv = *(const u16x4*)(xb + (size_t)n * IN_C + c0);
    u16x4 o;
#pragma unroll
    for (int j = 0; j < 4; j++) o[j] = f2bf(fmaf(ep, bf2f(xv[j]), acc[j]));
    *(u16x4*)(A0 + (size_t)n * IN_C + c0) = o;
}

// L2: A1 = bf16((1+eps2)*h1 + sum h1[src]),  512 bf16 channels, fp32 accumulate
__global__ __launch_bounds__(256) void k_agg_l2(
    const u16* __restrict__ h, const int* __restrict__ rp,
    const int* __restrict__ col, const float* __restrict__ eps,
    u16* __restrict__ A1) {
    int wave = threadIdx.x >> 6, lane = threadIdx.x & 63;
    int n = blockIdx.x * 4 + wave;
    if (n >= N_NODES) return;
    int rs = rp[n], re = rp[n + 1];
    int c0 = lane * 8;
    float acc[8] = {0.f, 0.f, 0.f, 0.f, 0.f, 0.f, 0.f, 0.f};
    for (int e = rs; e < re; e++) {
        int s = col[e];
        u16x8 v = *(const u16x8*)(h + (size_t)s * HID_C + c0);
#pragma unroll
        for (int j = 0; j < 8; j++) acc[j] += bf2f(v[j]);
    }
    float ep = 1.f + eps[0];
    u16x8 hv = *(const u16x8*)(h + (size_t)n * HID_C + c0);
    u16x8 o;
#pragma unroll
    for (int j = 0; j < 8; j++) o[j] = f2bf(fmaf(ep, bf2f(hv[j]), acc[j]));
    *(u16x8*)(A1 + (size_t)n * HID_C + c0) = o;
}

// L3 (post-GEMM): out = (1+eps3)*g3 + sum g3[src] + b3,  256 bf16 channels -> fp32 out
__global__ __launch_bounds__(256) void k_agg_l3(
    const u16* __restrict__ g, const int* __restrict__ rp,
    const int* __restrict__ col, const float* __restrict__ eps,
    const float* __restrict__ b, float* __restrict__ out) {
    int wave = threadIdx.x >> 6, lane = threadIdx.x & 63;
    int n = blockIdx.x * 4 + wave;
    if (n >= N_NODES) return;
    int rs = rp[n], re = rp[n + 1];
    int c0 = lane * 4;
    float acc[4] = {0.f, 0.f, 0.f, 0.f};
    for (int e = rs; e < re; e++) {
        int s = col[e];
        u16x4 v = *(const u16x4*)(g + (size_t)s * OUT_C + c0);
#pragma unroll
        for (int j = 0; j < 4; j++) acc[j] += bf2f(v[j]);
    }
    float ep = 1.f + eps[0];
    u16x4 gv = *(const u16x4*)(g + (size_t)n * OUT_C + c0);
    float4 bv = *(const float4*)(b + c0);
    float4 o;
    o.x = fmaf(ep, bf2f(gv[0]), acc[0]) + bv.x;
    o.y = fmaf(ep, bf2f(gv[1]), acc[1]) + bv.y;
    o.z = fmaf(ep, bf2f(gv[2]), acc[2]) + bv.z;
    o.w = fmaf(ep, bf2f(gv[3]), acc[3]) + bv.w;
    *(float4*)(out + (size_t)n * OUT_C + c0) = o;
}

// -------------- bf16 MFMA GEMM: C[M][N] = A[M][K] @ Wt[N][K]^T --------------
// 128x128 tile, BK=32, 4 waves (2x2), global_load_lds staging with both-sides
// XOR chunk swizzle (rule 21): LDS tile [128 rows][32 bf16], row=64B=4 chunks,
// chunk c' = c ^ swz4(row) gives 2-way (free) bank access on ds_read_b128.
// EPI=0: out bf16 = relu(acc + bias).  EPI=1: out bf16 = acc (no bias/relu).
template <int K, int EPI>
__global__ __launch_bounds__(256, 2) void gemm_k(
    const u16* __restrict__ A, const u16* __restrict__ Wt,
    const float* __restrict__ bias, void* __restrict__ out,
    int N, int grid_n) {
    __shared__ u16 Als[128 * 32];
    __shared__ u16 Bls[128 * 32];
    const int tid  = threadIdx.x;
    const int wave = tid >> 6, lane = tid & 63;
    const int wm = wave >> 1, wn = wave & 1;
    const int bm = blockIdx.x / grid_n, bn = blockIdx.x % grid_n;
    const int m0 = bm * 128, n0 = bn * 128;
    const int sr = lane >> 2, sc = lane & 3;       // staging: 16 rows x 4 chunks
    const int fr = lane & 15, kg = lane >> 4;      // fragment coords

    f32x4 acc[4][4];
#pragma unroll
    for (int i = 0; i < 4; i++)
#pragma unroll
        for (int j = 0; j < 4; j++) acc[i][j] = (f32x4){0.f, 0.f, 0.f, 0.f};

    for (int kk = 0; kk < K; kk += 32) {
#pragma unroll
        for (int i = 0; i < 2; i++) {
            int rl = wave * 32 + i * 16 + sr;
            int c  = sc ^ swz4(rl);                 // pre-swizzled global source
            gload16(A  + (size_t)(m0 + rl) * K + kk + c * 8,
                    &Als[(wave * 32 + i * 16) * 32]);
            gload16(Wt + (size_t)(n0 + rl) * K + kk + c * 8,
                    &Bls[(wave * 32 + i * 16) * 32]);
        }
        asm volatile("s_waitcnt vmcnt(0)" ::: "memory");
        __syncthreads();

        s16x8 af[4], bfr[4];
#pragma unroll
        for (int mi = 0; mi < 4; mi++) {
            int r = wm * 64 + mi * 16 + fr;
            int c = kg ^ swz4(r);                   // swizzled read
            af[mi] = *(const s16x8*)&Als[r * 32 + c * 8];
        }
#pragma unroll
        for (int ni = 0; ni < 4; ni++) {
            int r = wn * 64 + ni * 16 + fr;
            int c = kg ^ swz4(r);
            bfr[ni] = *(const s16x8*)&Bls[r * 32 + c * 8];
        }
#pragma unroll
        for (int mi = 0; mi < 4; mi++)
#pragma unroll
            for (int ni = 0; ni < 4; ni++)
                acc[mi][ni] = __builtin_amdgcn_mfma_f32_16x16x32_bf16(
                    af[mi], bfr[ni], acc[mi][ni], 0, 0, 0);
        __syncthreads();
    }

    // epilogue: C row = kg*4 + j, col = fr (m89/m91-verified C/D layout)
#pragma unroll
    for (int ni = 0; ni < 4; ni++) {
        int cn = n0 + wn * 64 + ni * 16 + fr;
        float bv = 0.f;
        if constexpr (EPI == 0) bv = bias[cn];
#pragma unroll
        for (int mi = 0; mi < 4; mi++) {
            int rb = m0 + wm * 64 + mi * 16 + kg * 4;
#pragma unroll
            for (int j = 0; j < 4; j++) {
                int r = rb + j;
                if (r < N_NODES) {
                    float v = acc[mi][ni][j];
                    if constexpr (EPI == 0) {
                        v += bv;
                        v = v > 0.f ? v : 0.f;
                        ((u16*)out)[(size_t)r * N + cn] = f2bf(v);
                    } else {
                        ((u16*)out)[(size_t)r * N + cn] = f2bf(v);
                    }
                }
            }
        }
    }
}

// ---------------- launch ----------------
extern "C" void kernel_launch(void* const* d_in, const int* in_sizes, int n_in,
                              void* d_out, int out_size, void* d_ws, size_t ws_size,
                              hipStream_t stream) {
    const float* x    = (const float*)d_in[0];
    const int*   src  = (const int*)d_in[1];
    const int*   dst  = (const int*)d_in[2];
    const float* w1   = (const float*)d_in[3];
    const float* b1   = (const float*)d_in[4];
    const float* eps1 = (const float*)d_in[5];
    const float* w2   = (const float*)d_in[6];
    const float* b2   = (const float*)d_in[7];
    const float* eps2 = (const float*)d_in[8];
    const float* w3   = (const float*)d_in[9];
    const float* b3   = (const float*)d_in[10];
    const float* eps3 = (const float*)d_in[11];

    char* ws = (char*)d_ws;
    size_t off = 0;
    auto take = [&](size_t bytes) {
        char* p = ws + off;
        off += (bytes + 255) & ~(size_t)255;
        return p;
    };
    int* cnt  = (int*)take((size_t)N_NODES * 4);
    int* rp   = (int*)take((size_t)(N_NODES + 1) * 4);
    int* cur  = (int*)take((size_t)N_NODES * 4);
    int* bsum = (int*)take(256 * 4);
    int* col  = (int*)take((size_t)N_EDGES * 4);
    u16* w1t  = (u16*)take((size_t)IN_C * HID_C * 2);
    u16* w2t  = (u16*)take((size_t)HID_C * HID_C * 2);
    u16* w3t  = (u16*)take((size_t)HID_C * OUT_C * 2);
    u16* A0   = (u16*)take((size_t)M_PAD * IN_C * 2);
    u16* h1   = (u16*)take((size_t)M_PAD * HID_C * 2);
    u16* A1   = (u16*)take((size_t)M_PAD * HID_C * 2);
    // time-shared buffer: xb (phase 1) -> A1 (phase 2) -> g3 bf16 (phase 3).
    // each is fully dead before the next is written; stream order serializes.
    u16* xb = A1;            // 25.6 MB <= 51.2 MB, dead after k_agg_l1
    u16* h2 = h1;            // GEMM2 reads only A1 -> safe alias
    u16* g3 = A1;            // GEMM3 reads only h2 -> safe alias

    const int NB = 196;  // ceil(50000/256)

    hipMemsetAsync(cnt, 0, (size_t)N_NODES * 4, stream);
    k_hist   <<<(N_EDGES + 255) / 256, 256, 0, stream>>>(dst, cnt);
    k_partial<<<NB, 256, 0, stream>>>(cnt, bsum);
    k_scanb  <<<1, 256, 0, stream>>>(bsum, NB);
    k_rowptr <<<NB, 256, 0, stream>>>(cnt, bsum, rp, cur);
    k_scatter<<<(N_EDGES + 255) / 256, 256, 0, stream>>>(src, dst, cur, col);

    k_wt<<<(IN_C * HID_C + 255) / 256, 256, 0, stream>>>(w1, w1t, IN_C, HID_C);
    k_wt<<<(HID_C * HID_C + 255) / 256, 256, 0, stream>>>(w2, w2t, HID_C, HID_C);
    k_wt<<<(HID_C * OUT_C + 255) / 256, 256, 0, stream>>>(w3, w3t, HID_C, OUT_C);
    k_x2bf<<<(N_NODES * IN_C / 4 + 255) / 256, 256, 0, stream>>>(x, xb);

    // layer 1: aggregate (256ch bf16) then GEMM -> h1 = relu(A0 @ W1 + b1)
    k_agg_l1<<<12500, 256, 0, stream>>>(xb, rp, col, eps1, A0);
    gemm_k<IN_C, 0><<<391 * (HID_C / 128), 256, 0, stream>>>(
        A0, w1t, b1, h1, HID_C, HID_C / 128);

    // layer 2: aggregate (512ch) then GEMM -> h2 = relu(A1 @ W2 + b2)
    k_agg_l2<<<12500, 256, 0, stream>>>(h1, rp, col, eps2, A1);
    gemm_k<HID_C, 0><<<391 * (HID_C / 128), 256, 0, stream>>>(
        A1, w2t, b2, h2, HID_C, HID_C / 128);

    // layer 3: GEMM first (g3 = h2 @ W3 bf16, no bias), then aggregate (256ch) + bias
    gemm_k<HID_C, 1><<<391 * (OUT_C / 128), 256, 0, stream>>>(
        h2, w3t, nullptr, g3, OUT_C, OUT_C / 128);
    k_agg_l3<<<12500, 256, 0, stream>>>(g3, rp, col, eps3, b3, (float*)d_out);
}